// Round 1
// baseline (565.311 us; speedup 1.0000x reference)
//
#include <hip/hip_runtime.h>

#define CUT 32

// W2[n][m] = (re, im) of kerr[m] * G[m][n], interleaved. 8 KiB.
__device__ __align__(16) float g_W2[CUT * CUT * 2];

// ---------------------------------------------------------------------------
// Kernel A: build the Gaussian-unitary matrix (with Kerr folded in) in fp64.
// One wave. Lane m (m < 32) owns row m of the current column.
// ---------------------------------------------------------------------------
__global__ __launch_bounds__(64) void build_W(
    const float* __restrict__ gre, const float* __restrict__ gim,
    const float* __restrict__ phi_p, const float* __restrict__ zre,
    const float* __restrict__ zim, const float* __restrict__ kap)
{
    const int lane = threadIdx.x;

    const double gr = (double)gre[0], gi = (double)gim[0];
    const double ph = (double)phi_p[0];
    const double zr = (double)zre[0], zi = (double)zim[0];
    const double kp = (double)kap[0];

    const double r     = sqrt(zr * zr + zi * zi);
    const double delta = atan2(zi, zr);
    const double T     = tanh(r);
    const double sech  = 1.0 / cosh(r);

    const double adp = delta + 2.0 * ph;
    const double edr = cos(adp), edi = sin(adp);   // e^{i(delta+2phi)}

    // g00 = exp(-0.5*(|g|^2 + conj(g)^2 * eidp * T)) * sqrt(sech)
    const double cg2r = gr * gr - gi * gi, cg2i = -2.0 * gr * gi;
    const double wr_  = (cg2r * edr - cg2i * edi) * T;
    const double wi_  = (cg2r * edi + cg2i * edr) * T;
    const double exr  = -0.5 * (gr * gr + gi * gi + wr_);
    const double exi  = -0.5 * wi_;
    const double mag  = exp(exr) * sqrt(sech);
    const double g00r = mag * cos(exi), g00i = mag * sin(exi);

    // A = gamma + conj(gamma)*eidp*T ; B = eidp*T
    const double cgTr = (gr * edr + gi * edi) * T;
    const double cgTi = (gr * edi - gi * edr) * T;
    const double Ar = gr + cgTr, Ai = gi + cgTi;
    const double Br = edr * T,   Bi = edi * T;

    // per-lane sqrt tables (extracted with __shfl during the serial loops)
    const double dl  = (double)lane;
    const double sq  = sqrt(dl);                       // sqrt(lane)
    const double isq = (lane > 0) ? 1.0 / sq : 0.0;    // 1/sqrt(lane)

    // ---- column 0: serial three-term recurrence in m (uniform values) ----
    double cr = (lane == 0) ? g00r : 0.0;
    double ci = (lane == 0) ? g00i : 0.0;
    double g1r = g00r, g1i = g00i, g2r = 0.0, g2i = 0.0;
    for (int m = 1; m < CUT; ++m) {
        const double sm1 = __shfl(sq, m - 1);
        const double ism = __shfl(isq, m);
        double tr = Ar * g1r - Ai * g1i - sm1 * (Br * g2r - Bi * g2i);
        double ti = Ar * g1i + Ai * g1r - sm1 * (Br * g2i + Bi * g2r);
        tr *= ism; ti *= ism;
        if (lane == m) { cr = tr; ci = ti; }
        g2r = g1r; g2i = g1i; g1r = tr; g1i = ti;
    }

    const double Pr = cos(ph) * sech,  Pi = sin(ph) * sech;   // e^{i phi} sech
    const double Qr = cos(delta) * T,  Qi = -sin(delta) * T;  // e^{-i delta} tanh
    const double gbr = gr, gbi = -gi;                         // conj(gamma)

    // Kerr factor for row m = lane: e^{i kappa m^2}
    const double ka = kp * dl * dl;
    const double kr = cos(ka), ki = sin(ka);

    if (lane < CUT) {
        g_W2[(0 * CUT + lane) * 2 + 0] = (float)(kr * cr - ki * ci);
        g_W2[(0 * CUT + lane) * 2 + 1] = (float)(kr * ci + ki * cr);
    }

    // ---- columns n -> n+1: parallel in m, shift via shfl_up ----
    double pr = 0.0, pi = 0.0;
    for (int n = 0; n < CUT - 1; ++n) {
        double upr = __shfl_up(cr, 1);
        double upi = __shfl_up(ci, 1);
        if (lane == 0) { upr = 0.0; upi = 0.0; }
        const double sn   = __shfl(sq, n);
        const double isn1 = __shfl(isq, n + 1);
        // t = sqrt(m)*c[m-1] - conj(gamma)*c[m]
        const double tr = sq * upr - (gbr * cr - gbi * ci);
        const double ti = sq * upi - (gbr * ci + gbi * cr);
        // u = (P*t + Q*sqrt(n)*c_prev) / sqrt(n+1)
        double ur = (Pr * tr - Pi * ti + sn * (Qr * pr - Qi * pi)) * isn1;
        double ui = (Pr * ti + Pi * tr + sn * (Qr * pi + Qi * pr)) * isn1;
        if (lane < CUT) {
            g_W2[((n + 1) * CUT + lane) * 2 + 0] = (float)(kr * ur - ki * ui);
            g_W2[((n + 1) * CUT + lane) * 2 + 1] = (float)(kr * ui + ki * ur);
        }
        pr = cr; pi = ci; cr = ur; ci = ui;
    }
}

// ---------------------------------------------------------------------------
// Kernel B: out[b,m] = sum_n W[m,n] * state[b,n], 2 rows per thread.
// ---------------------------------------------------------------------------
__global__ __launch_bounds__(256) void apply_W(
    const float* __restrict__ sre, const float* __restrict__ sim,
    float* __restrict__ out, int batch)
{
    __shared__ __align__(16) float W[CUT * CUT * 2];
    const int t = threadIdx.x;
    {
        const float4* src = (const float4*)g_W2;
        float4* dst = (float4*)W;
        dst[t]       = src[t];
        dst[t + 256] = src[t + 256];
    }
    __syncthreads();

    const long r0 = (long)blockIdx.x * 512 + t;
    if (r0 >= batch) return;
    const long r1 = r0 + 256;
    const bool v1 = (r1 < batch);
    const long rr1 = v1 ? r1 : r0;

    const float4* sre4 = (const float4*)sre;
    const float4* sim4 = (const float4*)sim;
    const long b0 = r0 * 8, b1 = rr1 * 8;

    float ar[2][CUT], ai[2][CUT];
    #pragma unroll
    for (int m = 0; m < CUT; ++m) {
        ar[0][m] = 0.f; ar[1][m] = 0.f; ai[0][m] = 0.f; ai[1][m] = 0.f;
    }

    // software-pipelined n-chunks of 4 (one float4 of re + im per row)
    float4 nre0 = sre4[b0], nim0 = sim4[b0];
    float4 nre1 = sre4[b1], nim1 = sim4[b1];

    #pragma unroll 1
    for (int c = 0; c < 8; ++c) {
        const float4 cre0 = nre0, cim0 = nim0, cre1 = nre1, cim1 = nim1;
        if (c < 7) {
            nre0 = sre4[b0 + c + 1]; nim0 = sim4[b0 + c + 1];
            nre1 = sre4[b1 + c + 1]; nim1 = sim4[b1 + c + 1];
        }
        const float sr[2][4] = {{cre0.x, cre0.y, cre0.z, cre0.w},
                                {cre1.x, cre1.y, cre1.z, cre1.w}};
        const float si[2][4] = {{cim0.x, cim0.y, cim0.z, cim0.w},
                                {cim1.x, cim1.y, cim1.z, cim1.w}};
        #pragma unroll
        for (int j = 0; j < 4; ++j) {
            const float* Wn = &W[(c * 4 + j) * (2 * CUT)];
            #pragma unroll
            for (int m2 = 0; m2 < 16; ++m2) {
                const float4 wv = *(const float4*)&Wn[4 * m2]; // (wr,wi) x2
                const int m = 2 * m2;
                #pragma unroll
                for (int q = 0; q < 2; ++q) {
                    ar[q][m]     = fmaf(wv.x, sr[q][j], fmaf(-wv.y, si[q][j], ar[q][m]));
                    ai[q][m]     = fmaf(wv.x, si[q][j], fmaf( wv.y, sr[q][j], ai[q][m]));
                    ar[q][m + 1] = fmaf(wv.z, sr[q][j], fmaf(-wv.w, si[q][j], ar[q][m + 1]));
                    ai[q][m + 1] = fmaf(wv.z, si[q][j], fmaf( wv.w, sr[q][j], ai[q][m + 1]));
                }
            }
        }
    }

    float4* o4 = (float4*)out;
    const long o0 = r0 * 16;
    #pragma unroll
    for (int m2 = 0; m2 < 16; ++m2) {
        o4[o0 + m2] = make_float4(ar[0][2 * m2], ai[0][2 * m2],
                                  ar[0][2 * m2 + 1], ai[0][2 * m2 + 1]);
    }
    if (v1) {
        const long o1 = r1 * 16;
        #pragma unroll
        for (int m2 = 0; m2 < 16; ++m2) {
            o4[o1 + m2] = make_float4(ar[1][2 * m2], ai[1][2 * m2],
                                      ar[1][2 * m2 + 1], ai[1][2 * m2 + 1]);
        }
    }
}

extern "C" void kernel_launch(void* const* d_in, const int* in_sizes, int n_in,
                              void* d_out, int out_size, void* d_ws, size_t ws_size,
                              hipStream_t stream) {
    const float* sre = (const float*)d_in[0];
    const float* sim = (const float*)d_in[1];
    const int batch = in_sizes[0] / CUT;

    build_W<<<1, 64, 0, stream>>>((const float*)d_in[2], (const float*)d_in[3],
                                  (const float*)d_in[4], (const float*)d_in[5],
                                  (const float*)d_in[6], (const float*)d_in[7]);

    const int blocks = (batch + 511) / 512;
    apply_W<<<blocks, 256, 0, stream>>>(sre, sim, (float*)d_out, batch);
}